// Round 1
// baseline (943.483 us; speedup 1.0000x reference)
//
#include <hip/hip_runtime.h>

#define N_    2
#define LQ_   21760
#define D_    256
#define M_    8
#define L_    4
#define P_    4
#define DH_   32
#define LEN_  21760

__constant__ int c_start[4] = {0, 16384, 20480, 21504};
__constant__ int c_HW[4]    = {128, 64, 32, 16};

// ---------------- Kernel A: value projection ----------------
// v = value @ W_val + b_val, stored as vout[((n*8+m)*LEN_ + pix)*32 + d]
__global__ __launch_bounds__(256) void vproj_kernel(
    const float* __restrict__ value, const float* __restrict__ Wv,
    const float* __restrict__ bv, float* __restrict__ vout) {
  __shared__ float vs[8][256];
  const int t  = threadIdx.x;
  const int r0 = blockIdx.x * 8;  // row = n*LEN_ + pix
#pragma unroll
  for (int r = 0; r < 8; ++r) vs[r][t] = value[(size_t)(r0 + r) * D_ + t];
  __syncthreads();

  float acc[8] = {};
  for (int k = 0; k < D_; ++k) {
    float w = Wv[k * D_ + t];
#pragma unroll
    for (int r = 0; r < 8; ++r) acc[r] += vs[r][k] * w;
  }
  const float bb = bv[t];
  const int m = t >> 5, d = t & 31;
#pragma unroll
  for (int r = 0; r < 8; ++r) {
    int row = r0 + r;
    int n   = row / LEN_;
    int pix = row - n * LEN_;
    vout[(((size_t)(n * M_ + m) * LEN_) + pix) * DH_ + d] = acc[r] + bb;
  }
}

// ---------------- Kernel B: fused offsets/attn/sample/out ----------------
__global__ __launch_bounds__(256) void msda_kernel(
    const float* __restrict__ query, const float* __restrict__ refp,
    const float* __restrict__ Woff, const float* __restrict__ boff,
    const float* __restrict__ Watt, const float* __restrict__ batt,
    const float* __restrict__ Wout, const float* __restrict__ bout,
    const float* __restrict__ vproj, float* __restrict__ out) {
  __shared__ float qs[8][256];
  __shared__ float mid[8][256];
  __shared__ float off_sm[256];
  __shared__ float aw_sm[128];
  __shared__ int   idx_sm[128][4];
  __shared__ float w_sm[128][4];

  const int t   = threadIdx.x;
  const int qg0 = blockIdx.x * 8;   // global row = n*LQ + q  (LQ%8==0 -> same n)
  const int n   = qg0 / LQ_;

#pragma unroll
  for (int r = 0; r < 8; ++r) qs[r][t] = query[(size_t)(qg0 + r) * D_ + t];
  __syncthreads();

  // ---- offset (256 cols) + attn (128 cols) projections, 8 queries each ----
  float offa[8] = {};
  float atta[8] = {};
  if (t < 128) {
    for (int k = 0; k < D_; ++k) {
      float w1 = Woff[k * 256 + t];
      float w2 = Watt[k * 128 + t];
#pragma unroll
      for (int r = 0; r < 8; ++r) {
        offa[r] += qs[r][k] * w1;
        atta[r] += qs[r][k] * w2;
      }
    }
  } else {
    for (int k = 0; k < D_; ++k) {
      float w1 = Woff[k * 256 + t];
#pragma unroll
      for (int r = 0; r < 8; ++r) offa[r] += qs[r][k] * w1;
    }
  }
  const float bo = boff[t];
  const float ba = (t < 128) ? batt[t] : 0.f;

  // ---- per-query: softmax, sample-param compute, gather-accumulate ----
  for (int r = 0; r < 8; ++r) {
    off_sm[t] = offa[r] + bo;
    if (t < 128) {
      float v = atta[r] + ba;
      float mx = v;
#pragma unroll
      for (int s = 8; s >= 1; s >>= 1) mx = fmaxf(mx, __shfl_xor(mx, s, 16));
      float e = __expf(v - mx);
      float sum = e;
#pragma unroll
      for (int s = 8; s >= 1; s >>= 1) sum += __shfl_xor(sum, s, 16);
      aw_sm[t] = e / sum;
    }
    __syncthreads();

    if (t < 128) {
      const int l  = (t >> 2) & 3;
      const int Wl = c_HW[l];
      const int st = c_start[l];
      const float rx = refp[(((size_t)(qg0 + r)) * L_ + l) * 2 + 0];
      const float ry = refp[(((size_t)(qg0 + r)) * L_ + l) * 2 + 1];
      const float gx = rx * (float)Wl + off_sm[2 * t]     - 0.5f;
      const float gy = ry * (float)Wl + off_sm[2 * t + 1] - 0.5f;
      const float fx0 = floorf(gx), fy0 = floorf(gy);
      const int x0 = (int)fx0, y0 = (int)fy0;
      const float wx1 = gx - fx0, wy1 = gy - fy0;
      const float wx0 = 1.f - wx1, wy0 = 1.f - wy1;
      const float a = aw_sm[t];
      const bool vx0 = (x0 >= 0) && (x0 < Wl);
      const bool vx1 = (x0 + 1 >= 0) && (x0 + 1 < Wl);
      const bool vy0 = (y0 >= 0) && (y0 < Wl);
      const bool vy1 = (y0 + 1 >= 0) && (y0 + 1 < Wl);
      idx_sm[t][0] = (vx0 && vy0) ? st + y0 * Wl + x0 : -1;
      idx_sm[t][1] = (vx1 && vy0) ? st + y0 * Wl + x0 + 1 : -1;
      idx_sm[t][2] = (vx0 && vy1) ? st + (y0 + 1) * Wl + x0 : -1;
      idx_sm[t][3] = (vx1 && vy1) ? st + (y0 + 1) * Wl + x0 + 1 : -1;
      w_sm[t][0] = wy0 * wx0 * a;
      w_sm[t][1] = wy0 * wx1 * a;
      w_sm[t][2] = wy1 * wx0 * a;
      w_sm[t][3] = wy1 * wx1 * a;
    }
    __syncthreads();

    {
      const int m = t >> 5, d = t & 31;
      const float* vbase = vproj + ((size_t)(n * M_ + m) * LEN_) * DH_ + d;
      float acc = 0.f;
#pragma unroll
      for (int s = 0; s < 16; ++s) {
        int sid = m * 16 + s;
#pragma unroll
        for (int c = 0; c < 4; ++c) {
          int ix = idx_sm[sid][c];
          float wc = w_sm[sid][c];
          if (ix >= 0) acc += vbase[(size_t)ix * DH_] * wc;
        }
      }
      mid[r][t] = acc;
    }
    __syncthreads();
  }

  // ---- output projection: out = mid @ W_out + b_out ----
  float oacc[8] = {};
  for (int k = 0; k < D_; ++k) {
    float w = Wout[k * D_ + t];
#pragma unroll
    for (int r = 0; r < 8; ++r) oacc[r] += mid[r][k] * w;
  }
  const float bb = bout[t];
#pragma unroll
  for (int r = 0; r < 8; ++r)
    out[(size_t)(qg0 + r) * D_ + t] = oacc[r] + bb;
}

extern "C" void kernel_launch(void* const* d_in, const int* in_sizes, int n_in,
                              void* d_out, int out_size, void* d_ws, size_t ws_size,
                              hipStream_t stream) {
  const float* query = (const float*)d_in[0];
  const float* refp  = (const float*)d_in[1];
  const float* value = (const float*)d_in[2];
  // d_in[3] = value_spatial_shapes (static, hardcoded)
  const float* Wv   = (const float*)d_in[4];
  const float* bv   = (const float*)d_in[5];
  const float* Woff = (const float*)d_in[6];
  const float* boff = (const float*)d_in[7];
  const float* Watt = (const float*)d_in[8];
  const float* batt = (const float*)d_in[9];
  const float* Wout = (const float*)d_in[10];
  const float* bout = (const float*)d_in[11];
  float* out = (float*)d_out;

  float* vproj = (float*)d_ws;  // N*M*LEN_*DH_ floats = 42.5 MiB

  dim3 blk(256);
  dim3 grdA((N_ * LEN_) / 8);   // 5440
  dim3 grdB((N_ * LQ_) / 8);    // 5440

  hipLaunchKernelGGL(vproj_kernel, grdA, blk, 0, stream, value, Wv, bv, vproj);
  hipLaunchKernelGGL(msda_kernel, grdB, blk, 0, stream,
                     query, refp, Woff, boff, Watt, batt, Wout, bout, vproj, out);
}

// Round 2
// 621.830 us; speedup vs baseline: 1.5173x; 1.5173x over previous
//
#include <hip/hip_runtime.h>

typedef __attribute__((ext_vector_type(8))) short short8;
typedef __attribute__((ext_vector_type(4))) float floatx4;

#define N_    2
#define LQ_   21760
#define D_    256
#define M_    8
#define L_    4
#define P_    4
#define DH_   32
#define LEN_  21760
#define BQ    32

__constant__ int c_start[4] = {0, 16384, 20480, 21504};
__constant__ int c_HW[4]    = {128, 64, 32, 16};

// ws layout (bytes):
//   vproj bf16 [N*M][LEN_][32]          @ 0        (22,282,240 B)
//   wt bf16: Wofft[256][256] @ elem 0, Wattt[128][256] @ 65536,
//            Woutt[256][256] @ 98304,   Wvt[256][256]  @ 163840
#define WT_BYTE_OFF 22282240u

__device__ __forceinline__ unsigned short f2bf(float f) {
  unsigned int u = __builtin_bit_cast(unsigned int, f);
  u += 0x7fffu + ((u >> 16) & 1u);   // RNE
  return (unsigned short)(u >> 16);
}
__device__ __forceinline__ float bf2f(unsigned short s) {
  return __builtin_bit_cast(float, ((unsigned int)s) << 16);
}

// ---------------- prep: transpose + convert weights to bf16 ----------------
__global__ __launch_bounds__(256) void prep_kernel(
    const float* __restrict__ Woff, const float* __restrict__ Watt,
    const float* __restrict__ Wout, const float* __restrict__ Wv,
    unsigned short* __restrict__ wt) {
  const int b = blockIdx.x, t = threadIdx.x;
  const float* src; int ncols, n; unsigned short* dst;
  if (b < 256)      { src = Woff; ncols = 256; n = b;       dst = wt + 0      + n * 256; }
  else if (b < 384) { src = Watt; ncols = 128; n = b - 256; dst = wt + 65536  + n * 256; }
  else if (b < 640) { src = Wout; ncols = 256; n = b - 384; dst = wt + 98304  + n * 256; }
  else              { src = Wv;   ncols = 256; n = b - 640; dst = wt + 163840 + n * 256; }
  dst[t] = f2bf(src[(size_t)t * ncols + n]);
}

// ---------------- vproj: value @ W_val + b_val -> bf16 [n][m][pix][32] -----
__global__ __launch_bounds__(256, 2) void vproj_kernel(
    const float* __restrict__ value, const unsigned short* __restrict__ Wvt,
    const float* __restrict__ bv, unsigned short* __restrict__ vout) {
  __shared__ unsigned short vs[64][264];
  const int t = threadIdx.x;
  const int r0 = blockIdx.x * 64;
  {
    const int c2 = (t & 127) * 2;
    const int rb = t >> 7;
#pragma unroll
    for (int i = 0; i < 32; ++i) {
      int rr = rb + i * 2;
      float2 v = *(const float2*)(value + (size_t)(r0 + rr) * D_ + c2);
      *(unsigned int*)&vs[rr][c2] = (unsigned int)f2bf(v.x) | ((unsigned int)f2bf(v.y) << 16);
    }
  }
  __syncthreads();
  const int wave = t >> 6, lane = t & 63;
  const int arow = wave * 16 + (lane & 15);
  const int kg = (lane >> 4) * 8;
  floatx4 acc[16] = {};
  for (int kk = 0; kk < 8; ++kk) {
    const int k0 = kk * 32;
    short8 af = *(const short8*)&vs[arow][k0 + kg];
#pragma unroll
    for (int ct = 0; ct < 16; ++ct) {
      const int col = ct * 16 + (lane & 15);
      short8 bf = *(const short8*)(Wvt + col * 256 + k0 + kg);
      acc[ct] = __builtin_amdgcn_mfma_f32_16x16x32_bf16(af, bf, acc[ct], 0, 0, 0);
    }
  }
  const int n = (r0 >= LEN_) ? 1 : 0;
  const int pixbase = r0 - n * LEN_ + wave * 16 + ((lane >> 4) * 4);
#pragma unroll
  for (int ct = 0; ct < 16; ++ct) {
    const int gc = ct * 16 + (lane & 15);
    const int m = gc >> 5, d = gc & 31;
    const float bb = bv[gc];
    unsigned short* ob = vout + ((size_t)(n * M_ + m) * LEN_) * DH_ + d;
#pragma unroll
    for (int j = 0; j < 4; ++j)
      ob[(size_t)(pixbase + j) * DH_] = f2bf(acc[ct][j] + bb);
  }
}

// ---------------- msda: fused proj/softmax/sample/out ----------------------
__global__ __launch_bounds__(256, 2) void msda_kernel(
    const float* __restrict__ query, const float* __restrict__ refp,
    const unsigned short* __restrict__ wt,
    const float* __restrict__ boff, const float* __restrict__ batt,
    const float* __restrict__ bout,
    const unsigned short* __restrict__ vproj, float* __restrict__ out) {
  __shared__ unsigned short qs[BQ][264];   // Q (bf16); reused as mid (bf16)
  __shared__ float oa[BQ][392];            // off [0..255], att->aw [256..383]
  __shared__ int   idx_sm[128][4];
  __shared__ float w_sm[128][4];

  const int t = threadIdx.x;
  const int qg0 = blockIdx.x * BQ;
  const int n = qg0 / LQ_;

  {  // stage Q -> bf16 LDS
    const int c2 = (t & 127) * 2;
    const int rb = t >> 7;
#pragma unroll
    for (int i = 0; i < 16; ++i) {
      int rr = rb + i * 2;
      float2 v = *(const float2*)(query + (size_t)(qg0 + rr) * D_ + c2);
      *(unsigned int*)&qs[rr][c2] = (unsigned int)f2bf(v.x) | ((unsigned int)f2bf(v.y) << 16);
    }
  }
  __syncthreads();

  const int wave = t >> 6, lane = t & 63;
  const int rt = wave & 1;
  const int arow = rt * 16 + (lane & 15);
  const int kg = (lane >> 4) * 8;

  {  // off+att GEMM: [32x256] @ [256x384]
    const int cb = (wave >> 1) * 192;
    floatx4 acc[12] = {};
    for (int kk = 0; kk < 8; ++kk) {
      const int k0 = kk * 32;
      short8 af = *(const short8*)&qs[arow][k0 + kg];
#pragma unroll
      for (int i = 0; i < 12; ++i) {
        const int col = cb + i * 16 + (lane & 15);
        const unsigned short* bp = (col < 256) ? (wt + col * 256)
                                               : (wt + 65536 + (col - 256) * 256);
        short8 bf = *(const short8*)(bp + k0 + kg);
        acc[i] = __builtin_amdgcn_mfma_f32_16x16x32_bf16(af, bf, acc[i], 0, 0, 0);
      }
    }
    const int row = rt * 16 + ((lane >> 4) * 4);
#pragma unroll
    for (int i = 0; i < 12; ++i) {
      const int col = cb + i * 16 + (lane & 15);
      const float bb = (col < 256) ? boff[col] : batt[col - 256];
#pragma unroll
      for (int j = 0; j < 4; ++j) oa[row + j][col] = acc[i][j] + bb;
    }
  }
  __syncthreads();

  {  // softmax over 16 per (q, m)
    const int q = t >> 3, m = t & 7;
    float v[16]; float mx = -1e30f;
#pragma unroll
    for (int s = 0; s < 16; ++s) { v[s] = oa[q][256 + m * 16 + s]; mx = fmaxf(mx, v[s]); }
    float sum = 0.f;
#pragma unroll
    for (int s = 0; s < 16; ++s) { v[s] = __expf(v[s] - mx); sum += v[s]; }
    const float inv = 1.f / sum;
#pragma unroll
    for (int s = 0; s < 16; ++s) oa[q][256 + m * 16 + s] = v[s] * inv;
  }
  __syncthreads();

  // sampling
  const int m_g = t >> 5;
  const int g = t & 31;
  const int p8 = g >> 3;             // corner 0..3
  const int d4 = (g & 7) * 4;        // 4 bf16 per lane
  const unsigned short* vbase = vproj + ((size_t)(n * M_ + m_g) * LEN_) * DH_ + d4;

  for (int q = 0; q < BQ; ++q) {
    if (t < 128) {
      const int l = (t >> 2) & 3;
      const int Wl = c_HW[l];
      const int st = c_start[l];
      const float rx = refp[(((size_t)(qg0 + q)) * L_ + l) * 2 + 0];
      const float ry = refp[(((size_t)(qg0 + q)) * L_ + l) * 2 + 1];
      const float gx = rx * (float)Wl + oa[q][2 * t]     - 0.5f;
      const float gy = ry * (float)Wl + oa[q][2 * t + 1] - 0.5f;
      const float fx0 = floorf(gx), fy0 = floorf(gy);
      const int x0 = (int)fx0, y0 = (int)fy0;
      const float wx1 = gx - fx0, wy1 = gy - fy0;
      const float wx0 = 1.f - wx1, wy0 = 1.f - wy1;
      const float a = oa[q][256 + t];
      const bool vx0 = (x0 >= 0) && (x0 < Wl);
      const bool vx1 = (x0 + 1 >= 0) && (x0 + 1 < Wl);
      const bool vy0 = (y0 >= 0) && (y0 < Wl);
      const bool vy1 = (y0 + 1 >= 0) && (y0 + 1 < Wl);
      idx_sm[t][0] = (vx0 && vy0) ? st + y0 * Wl + x0 : -1;
      idx_sm[t][1] = (vx1 && vy0) ? st + y0 * Wl + x0 + 1 : -1;
      idx_sm[t][2] = (vx0 && vy1) ? st + (y0 + 1) * Wl + x0 : -1;
      idx_sm[t][3] = (vx1 && vy1) ? st + (y0 + 1) * Wl + x0 + 1 : -1;
      w_sm[t][0] = wy0 * wx0 * a;
      w_sm[t][1] = wy0 * wx1 * a;
      w_sm[t][2] = wy1 * wx0 * a;
      w_sm[t][3] = wy1 * wx1 * a;
    }
    __syncthreads();

    float a0 = 0.f, a1 = 0.f, a2 = 0.f, a3 = 0.f;
    const int sidb = m_g * 16;
#pragma unroll
    for (int s = 0; s < 16; ++s) {
      const int ix = idx_sm[sidb + s][p8];
      const float wv = w_sm[sidb + s][p8];
      if (ix >= 0) {
        const unsigned short* p = vbase + (size_t)ix * DH_;
        const unsigned int u0 = *(const unsigned int*)p;
        const unsigned int u1 = *(const unsigned int*)(p + 2);
        a0 += __builtin_bit_cast(float, u0 << 16) * wv;
        a1 += __builtin_bit_cast(float, u0 & 0xffff0000u) * wv;
        a2 += __builtin_bit_cast(float, u1 << 16) * wv;
        a3 += __builtin_bit_cast(float, u1 & 0xffff0000u) * wv;
      }
    }
    a0 += __shfl_xor(a0, 8);  a1 += __shfl_xor(a1, 8);
    a2 += __shfl_xor(a2, 8);  a3 += __shfl_xor(a3, 8);
    a0 += __shfl_xor(a0, 16); a1 += __shfl_xor(a1, 16);
    a2 += __shfl_xor(a2, 16); a3 += __shfl_xor(a3, 16);
    if (g < 8) {
      unsigned int lo = (unsigned int)f2bf(a0) | ((unsigned int)f2bf(a1) << 16);
      unsigned int hi = (unsigned int)f2bf(a2) | ((unsigned int)f2bf(a3) << 16);
      unsigned int* mp = (unsigned int*)&qs[q][m_g * 32 + d4];
      mp[0] = lo; mp[1] = hi;
    }
    __syncthreads();
  }

  {  // out GEMM: mid [32x256] @ Wout [256x256]
    const int cb2 = (wave >> 1) * 128;
    floatx4 acc[8] = {};
    for (int kk = 0; kk < 8; ++kk) {
      const int k0 = kk * 32;
      short8 af = *(const short8*)&qs[arow][k0 + kg];
#pragma unroll
      for (int i = 0; i < 8; ++i) {
        const int col = cb2 + i * 16 + (lane & 15);
        short8 bf = *(const short8*)(wt + 98304 + col * 256 + k0 + kg);
        acc[i] = __builtin_amdgcn_mfma_f32_16x16x32_bf16(af, bf, acc[i], 0, 0, 0);
      }
    }
    const int row = rt * 16 + ((lane >> 4) * 4);
#pragma unroll
    for (int i = 0; i < 8; ++i) {
      const int col = cb2 + i * 16 + (lane & 15);
      const float bb = bout[col];
#pragma unroll
      for (int j = 0; j < 4; ++j)
        out[(size_t)(qg0 + row + j) * D_ + col] = acc[i][j] + bb;
    }
  }
}

extern "C" void kernel_launch(void* const* d_in, const int* in_sizes, int n_in,
                              void* d_out, int out_size, void* d_ws, size_t ws_size,
                              hipStream_t stream) {
  const float* query = (const float*)d_in[0];
  const float* refp  = (const float*)d_in[1];
  const float* value = (const float*)d_in[2];
  const float* Wv    = (const float*)d_in[4];
  const float* bv    = (const float*)d_in[5];
  const float* Woff  = (const float*)d_in[6];
  const float* boff  = (const float*)d_in[7];
  const float* Watt  = (const float*)d_in[8];
  const float* batt  = (const float*)d_in[9];
  const float* Wout  = (const float*)d_in[10];
  const float* bout  = (const float*)d_in[11];
  float* out = (float*)d_out;

  unsigned short* vproj = (unsigned short*)d_ws;
  unsigned short* wt    = (unsigned short*)((char*)d_ws + WT_BYTE_OFF);
  const unsigned short* Wvt = wt + 163840;

  dim3 blk(256);
  hipLaunchKernelGGL(prep_kernel, dim3(896), blk, 0, stream, Woff, Watt, Wout, Wv, wt);
  hipLaunchKernelGGL(vproj_kernel, dim3((N_ * LEN_) / 64), blk, 0, stream, value, Wvt, bv, vproj);
  hipLaunchKernelGGL(msda_kernel, dim3((N_ * LQ_) / BQ), blk, 0, stream,
                     query, refp, wt, boff, batt, bout, vproj, out);
}

// Round 5
// 338.772 us; speedup vs baseline: 2.7850x; 1.8355x over previous
//
#include <hip/hip_runtime.h>

typedef __attribute__((ext_vector_type(8))) short short8;
typedef __attribute__((ext_vector_type(4))) float floatx4;

#define N_    2
#define LQ_   21760
#define D_    256
#define M_    8
#define L_    4
#define P_    4
#define DH_   32
#define LEN_  21760
#define BQ    32

__constant__ int c_start[4] = {0, 16384, 20480, 21504};
__constant__ int c_HW[4]    = {128, 64, 32, 16};

// ws layout (bytes):
//   vproj bf16 [N*M][LEN_][32] @ 0  (22,282,240 B)
//   wt bf16: Wofft[256][256] @ elem 0, Wattt[128][256] @ 65536,
//            Woutt[256][256] @ 98304, Wvt[256][256] @ 163840
#define WT_BYTE_OFF 22282240u

__device__ __forceinline__ unsigned short f2bf(float f) {
  unsigned int u = __builtin_bit_cast(unsigned int, f);
  u += 0x7fffu + ((u >> 16) & 1u);   // RNE
  return (unsigned short)(u >> 16);
}

// ---------------- prep: transpose + convert weights to bf16 ----------------
__global__ __launch_bounds__(256) void prep_kernel(
    const float* __restrict__ Woff, const float* __restrict__ Watt,
    const float* __restrict__ Wout, const float* __restrict__ Wv,
    unsigned short* __restrict__ wt) {
  const int b = blockIdx.x, t = threadIdx.x;
  const float* src; int ncols, n; unsigned short* dst;
  if (b < 256)      { src = Woff; ncols = 256; n = b;       dst = wt + 0      + n * 256; }
  else if (b < 384) { src = Watt; ncols = 128; n = b - 256; dst = wt + 65536  + n * 256; }
  else if (b < 640) { src = Wout; ncols = 256; n = b - 384; dst = wt + 98304  + n * 256; }
  else              { src = Wv;   ncols = 256; n = b - 640; dst = wt + 163840 + n * 256; }
  dst[t] = f2bf(src[(size_t)t * ncols + n]);
}

// ---------------- vproj: value @ W_val + b_val -> bf16 [n][m][pix][32] -----
__global__ __launch_bounds__(256, 2) void vproj_kernel(
    const float* __restrict__ value, const unsigned short* __restrict__ Wvt,
    const float* __restrict__ bv, unsigned short* __restrict__ vout) {
  __shared__ unsigned short vs[64][264];
  const int t = threadIdx.x;
  const int r0 = blockIdx.x * 64;
  {
    const int c2 = (t & 127) * 2;
    const int rb = t >> 7;
#pragma unroll
    for (int i = 0; i < 32; ++i) {
      int rr = rb + i * 2;
      float2 v = *(const float2*)(value + (size_t)(r0 + rr) * D_ + c2);
      *(unsigned int*)&vs[rr][c2] = (unsigned int)f2bf(v.x) | ((unsigned int)f2bf(v.y) << 16);
    }
  }
  __syncthreads();
  const int wave = t >> 6, lane = t & 63;
  const int arow = wave * 16 + (lane & 15);
  const int kg = (lane >> 4) * 8;
  floatx4 acc[16] = {};
  for (int kk = 0; kk < 8; ++kk) {
    const int k0 = kk * 32;
    short8 af = *(const short8*)&vs[arow][k0 + kg];
#pragma unroll
    for (int ct = 0; ct < 16; ++ct) {
      const int col = ct * 16 + (lane & 15);
      short8 bf = *(const short8*)(Wvt + col * 256 + k0 + kg);
      acc[ct] = __builtin_amdgcn_mfma_f32_16x16x32_bf16(af, bf, acc[ct], 0, 0, 0);
    }
  }
  const int n = (r0 >= LEN_) ? 1 : 0;
  const int pixbase = r0 - n * LEN_ + wave * 16 + ((lane >> 4) * 4);
#pragma unroll
  for (int ct = 0; ct < 16; ++ct) {
    const int gc = ct * 16 + (lane & 15);
    const int m = gc >> 5, d = gc & 31;
    const float bb = bv[gc];
    unsigned short* ob = vout + ((size_t)(n * M_ + m) * LEN_) * DH_ + d;
#pragma unroll
    for (int j = 0; j < 4; ++j)
      ob[(size_t)(pixbase + j) * DH_] = f2bf(acc[ct][j] + bb);
  }
}

// ---------------- msda: fused proj/softmax/sample/out ----------------------
__global__ __launch_bounds__(256, 2) void msda_kernel(
    const float* __restrict__ query, const float* __restrict__ refp,
    const unsigned short* __restrict__ wt,
    const float* __restrict__ boff, const float* __restrict__ batt,
    const float* __restrict__ bout,
    const unsigned short* __restrict__ vproj, float* __restrict__ out) {
  __shared__ unsigned short qs[BQ][264];   // Q (bf16); reused as mid (bf16)
  __shared__ float oa[BQ][392];            // off [0..255], att->aw [256..383]
  __shared__ int   idx_sm[128][4];
  __shared__ float w_sm[128][4];

  const int t = threadIdx.x;
  const int qg0 = blockIdx.x * BQ;
  const int n = qg0 / LQ_;

  {  // stage Q -> bf16 LDS
    const int c2 = (t & 127) * 2;
    const int rb = t >> 7;
#pragma unroll
    for (int i = 0; i < 16; ++i) {
      int rr = rb + i * 2;
      float2 v = *(const float2*)(query + (size_t)(qg0 + rr) * D_ + c2);
      *(unsigned int*)&qs[rr][c2] = (unsigned int)f2bf(v.x) | ((unsigned int)f2bf(v.y) << 16);
    }
  }
  __syncthreads();

  const int wave = t >> 6, lane = t & 63;
  const int rt = wave & 1;
  const int arow = rt * 16 + (lane & 15);
  const int kg = (lane >> 4) * 8;

  {  // off+att GEMM: [32x256] @ [256x384]
    const int cb = (wave >> 1) * 192;
    floatx4 acc[12] = {};
    for (int kk = 0; kk < 8; ++kk) {
      const int k0 = kk * 32;
      short8 af = *(const short8*)&qs[arow][k0 + kg];
#pragma unroll
      for (int i = 0; i < 12; ++i) {
        const int col = cb + i * 16 + (lane & 15);
        const unsigned short* bp = (col < 256) ? (wt + col * 256)
                                               : (wt + 65536 + (col - 256) * 256);
        short8 bf = *(const short8*)(bp + k0 + kg);
        acc[i] = __builtin_amdgcn_mfma_f32_16x16x32_bf16(af, bf, acc[i], 0, 0, 0);
      }
    }
    const int row = rt * 16 + ((lane >> 4) * 4);
#pragma unroll
    for (int i = 0; i < 12; ++i) {
      const int col = cb + i * 16 + (lane & 15);
      const float bb = (col < 256) ? boff[col] : batt[col - 256];
#pragma unroll
      for (int j = 0; j < 4; ++j) oa[row + j][col] = acc[i][j] + bb;
    }
  }
  __syncthreads();

  {  // softmax over 16 per (q, m)
    const int q = t >> 3, m = t & 7;
    float v[16]; float mx = -1e30f;
#pragma unroll
    for (int s = 0; s < 16; ++s) { v[s] = oa[q][256 + m * 16 + s]; mx = fmaxf(mx, v[s]); }
    float sum = 0.f;
#pragma unroll
    for (int s = 0; s < 16; ++s) { v[s] = __expf(v[s] - mx); sum += v[s]; }
    const float inv = 1.f / sum;
#pragma unroll
    for (int s = 0; s < 16; ++s) oa[q][256 + m * 16 + s] = v[s] * inv;
  }
  __syncthreads();

  // sampling
  const int m_g = t >> 5;
  const int g = t & 31;
  const int p8 = g >> 3;             // corner 0..3
  const int d4 = (g & 7) * 4;        // 4 bf16 per lane
  const unsigned short* vbase = vproj + ((size_t)(n * M_ + m_g) * LEN_) * DH_ + d4;

  for (int q = 0; q < BQ; ++q) {
    if (t < 128) {
      const int l = (t >> 2) & 3;
      const int Wl = c_HW[l];
      const int st = c_start[l];
      const float rx = refp[(((size_t)(qg0 + q)) * L_ + l) * 2 + 0];
      const float ry = refp[(((size_t)(qg0 + q)) * L_ + l) * 2 + 1];
      const float gx = rx * (float)Wl + oa[q][2 * t]     - 0.5f;
      const float gy = ry * (float)Wl + oa[q][2 * t + 1] - 0.5f;
      const float fx0 = floorf(gx), fy0 = floorf(gy);
      const int x0 = (int)fx0, y0 = (int)fy0;
      const float wx1 = gx - fx0, wy1 = gy - fy0;
      const float wx0 = 1.f - wx1, wy0 = 1.f - wy1;
      const float a = oa[q][256 + t];
      const bool vx0 = (x0 >= 0) && (x0 < Wl);
      const bool vx1 = (x0 + 1 >= 0) && (x0 + 1 < Wl);
      const bool vy0 = (y0 >= 0) && (y0 < Wl);
      const bool vy1 = (y0 + 1 >= 0) && (y0 + 1 < Wl);
      idx_sm[t][0] = (vx0 && vy0) ? st + y0 * Wl + x0 : -1;
      idx_sm[t][1] = (vx1 && vy0) ? st + y0 * Wl + x0 + 1 : -1;
      idx_sm[t][2] = (vx0 && vy1) ? st + (y0 + 1) * Wl + x0 : -1;
      idx_sm[t][3] = (vx1 && vy1) ? st + (y0 + 1) * Wl + x0 + 1 : -1;
      w_sm[t][0] = wy0 * wx0 * a;
      w_sm[t][1] = wy0 * wx1 * a;
      w_sm[t][2] = wy1 * wx0 * a;
      w_sm[t][3] = wy1 * wx1 * a;
    }
    __syncthreads();

    float a0 = 0.f, a1 = 0.f, a2 = 0.f, a3 = 0.f;
    const int sidb = m_g * 16;
#pragma unroll
    for (int s = 0; s < 16; ++s) {
      const int ix = idx_sm[sidb + s][p8];
      const int ixc = (ix >= 0) ? ix : 0;
      const float wv = (ix >= 0) ? w_sm[sidb + s][p8] : 0.f;
      const unsigned short* p = vbase + (size_t)ixc * DH_;
      const uint2 u = *(const uint2*)p;
      a0 += __builtin_bit_cast(float, u.x << 16) * wv;
      a1 += __builtin_bit_cast(float, u.x & 0xffff0000u) * wv;
      a2 += __builtin_bit_cast(float, u.y << 16) * wv;
      a3 += __builtin_bit_cast(float, u.y & 0xffff0000u) * wv;
    }
    a0 += __shfl_xor(a0, 8);  a1 += __shfl_xor(a1, 8);
    a2 += __shfl_xor(a2, 8);  a3 += __shfl_xor(a3, 8);
    a0 += __shfl_xor(a0, 16); a1 += __shfl_xor(a1, 16);
    a2 += __shfl_xor(a2, 16); a3 += __shfl_xor(a3, 16);
    if (g < 8) {
      unsigned int* mp = (unsigned int*)&qs[q][m_g * 32 + d4];
      mp[0] = (unsigned int)f2bf(a0) | ((unsigned int)f2bf(a1) << 16);
      mp[1] = (unsigned int)f2bf(a2) | ((unsigned int)f2bf(a3) << 16);
    }
    __syncthreads();
  }

  {  // out GEMM: mid [32x256] @ Wout [256x256]
    const int cb2 = (wave >> 1) * 128;
    floatx4 acc[8] = {};
    for (int kk = 0; kk < 8; ++kk) {
      const int k0 = kk * 32;
      short8 af = *(const short8*)&qs[arow][k0 + kg];
#pragma unroll
      for (int i = 0; i < 8; ++i) {
        const int col = cb2 + i * 16 + (lane & 15);
        short8 bf = *(const short8*)(wt + 98304 + col * 256 + k0 + kg);
        acc[i] = __builtin_amdgcn_mfma_f32_16x16x32_bf16(af, bf, acc[i], 0, 0, 0);
      }
    }
    const int row = rt * 16 + ((lane >> 4) * 4);
#pragma unroll
    for (int i = 0; i < 8; ++i) {
      const int col = cb2 + i * 16 + (lane & 15);
      const float bb = bout[col];
#pragma unroll
      for (int j = 0; j < 4; ++j)
        out[(size_t)(qg0 + row + j) * D_ + col] = acc[i][j] + bb;
    }
  }
}

extern "C" void kernel_launch(void* const* d_in, const int* in_sizes, int n_in,
                              void* d_out, int out_size, void* d_ws, size_t ws_size,
                              hipStream_t stream) {
  const float* query = (const float*)d_in[0];
  const float* refp  = (const float*)d_in[1];
  const float* value = (const float*)d_in[2];
  const float* Wv    = (const float*)d_in[4];
  const float* bv    = (const float*)d_in[5];
  const float* Woff  = (const float*)d_in[6];
  const float* boff  = (const float*)d_in[7];
  const float* Watt  = (const float*)d_in[8];
  const float* batt  = (const float*)d_in[9];
  const float* Wout  = (const float*)d_in[10];
  const float* bout  = (const float*)d_in[11];
  float* out = (float*)d_out;

  unsigned short* vproj = (unsigned short*)d_ws;
  unsigned short* wt    = (unsigned short*)((char*)d_ws + WT_BYTE_OFF);
  const unsigned short* Wvt = wt + 163840;

  dim3 blk(256);
  hipLaunchKernelGGL(prep_kernel, dim3(896), blk, 0, stream, Woff, Watt, Wout, Wv, wt);
  hipLaunchKernelGGL(vproj_kernel, dim3((N_ * LEN_) / 64), blk, 0, stream, value, Wvt, bv, vproj);
  hipLaunchKernelGGL(msda_kernel, dim3((N_ * LQ_) / BQ), blk, 0, stream,
                     query, refp, wt, boff, batt, bout, vproj, out);
}

// Round 6
// 269.304 us; speedup vs baseline: 3.5034x; 1.2580x over previous
//
#include <hip/hip_runtime.h>

typedef __attribute__((ext_vector_type(8))) short short8;
typedef __attribute__((ext_vector_type(4))) float floatx4;

#define N_    2
#define LQ_   21760
#define D_    256
#define M_    8
#define L_    4
#define P_    4
#define DH_   32
#define LEN_  21760
#define BQ    16

__constant__ int c_start[4] = {0, 16384, 20480, 21504};
__constant__ int c_HW[4]    = {128, 64, 32, 16};

// ws layout (bytes):
//   vproj bf16 [N*M][LEN_][32] @ 0  (22,282,240 B)
//   wt bf16: Wofft[256][256] @ elem 0, Wattt[128][256] @ 65536,
//            Woutt[256][256] @ 98304, Wvt[256][256] @ 163840
#define WT_BYTE_OFF 22282240u

__device__ __forceinline__ unsigned short f2bf(float f) {
  unsigned int u = __builtin_bit_cast(unsigned int, f);
  u += 0x7fffu + ((u >> 16) & 1u);   // RNE
  return (unsigned short)(u >> 16);
}

// ---------------- prep: transpose + convert weights to bf16 ----------------
__global__ __launch_bounds__(256) void prep_kernel(
    const float* __restrict__ Woff, const float* __restrict__ Watt,
    const float* __restrict__ Wout, const float* __restrict__ Wv,
    unsigned short* __restrict__ wt) {
  const int b = blockIdx.x, t = threadIdx.x;
  const float* src; int ncols, n; unsigned short* dst;
  if (b < 256)      { src = Woff; ncols = 256; n = b;       dst = wt + 0      + n * 256; }
  else if (b < 384) { src = Watt; ncols = 128; n = b - 256; dst = wt + 65536  + n * 256; }
  else if (b < 640) { src = Wout; ncols = 256; n = b - 384; dst = wt + 98304  + n * 256; }
  else              { src = Wv;   ncols = 256; n = b - 640; dst = wt + 163840 + n * 256; }
  dst[t] = f2bf(src[(size_t)t * ncols + n]);
}

// ---------------- vproj: value @ W_val + b_val -> bf16 [n][m][pix][32] -----
__global__ __launch_bounds__(256, 2) void vproj_kernel(
    const float* __restrict__ value, const unsigned short* __restrict__ Wvt,
    const float* __restrict__ bv, unsigned short* __restrict__ vout) {
  __shared__ unsigned short vs[64][264];
  const int t = threadIdx.x;
  const int r0 = blockIdx.x * 64;
  {
    const int c2 = (t & 127) * 2;
    const int rb = t >> 7;
#pragma unroll
    for (int i = 0; i < 32; ++i) {
      int rr = rb + i * 2;
      float2 v = *(const float2*)(value + (size_t)(r0 + rr) * D_ + c2);
      *(unsigned int*)&vs[rr][c2] = (unsigned int)f2bf(v.x) | ((unsigned int)f2bf(v.y) << 16);
    }
  }
  __syncthreads();
  const int wave = t >> 6, lane = t & 63;
  const int arow = wave * 16 + (lane & 15);
  const int kg = (lane >> 4) * 8;
  floatx4 acc[16] = {};
  for (int kk = 0; kk < 8; ++kk) {
    const int k0 = kk * 32;
    short8 af = *(const short8*)&vs[arow][k0 + kg];
#pragma unroll
    for (int ct = 0; ct < 16; ++ct) {
      const int col = ct * 16 + (lane & 15);
      short8 bf = *(const short8*)(Wvt + col * 256 + k0 + kg);
      acc[ct] = __builtin_amdgcn_mfma_f32_16x16x32_bf16(af, bf, acc[ct], 0, 0, 0);
    }
  }
  const int n = (r0 >= LEN_) ? 1 : 0;
  const int pixbase = r0 - n * LEN_ + wave * 16 + ((lane >> 4) * 4);
#pragma unroll
  for (int ct = 0; ct < 16; ++ct) {
    const int gc = ct * 16 + (lane & 15);
    const int m = gc >> 5, d = gc & 31;
    const float bb = bv[gc];
    unsigned short* ob = vout + ((size_t)(n * M_ + m) * LEN_) * DH_ + d;
#pragma unroll
    for (int j = 0; j < 4; ++j)
      ob[(size_t)(pixbase + j) * DH_] = f2bf(acc[ct][j] + bb);
  }
}

// ---------------- msda: fused proj/softmax/sample/out ----------------------
__global__ __launch_bounds__(256, 4) void msda_kernel(
    const float* __restrict__ query, const float* __restrict__ refp,
    const unsigned short* __restrict__ wt,
    const float* __restrict__ boff, const float* __restrict__ batt,
    const float* __restrict__ bout,
    const unsigned short* __restrict__ vproj, float* __restrict__ out) {
  __shared__ unsigned short qs[BQ][264];   // Q (bf16); reused as mid (bf16)
  __shared__ float oa[BQ][388];            // off [0..255], att->aw [256..383]
  __shared__ short idxs[2][128][4];        // double-buffered sample params
  __shared__ float wls[2][128][4];

  const int t = threadIdx.x;
  const int qg0 = blockIdx.x * BQ;
  const int n = qg0 / LQ_;

  {  // stage Q -> bf16 LDS
    const int c2 = (t & 127) * 2;
    const int rb = t >> 7;
#pragma unroll
    for (int i = 0; i < 8; ++i) {
      int rr = rb + i * 2;
      float2 v = *(const float2*)(query + (size_t)(qg0 + rr) * D_ + c2);
      *(unsigned int*)&qs[rr][c2] = (unsigned int)f2bf(v.x) | ((unsigned int)f2bf(v.y) << 16);
    }
  }
  __syncthreads();

  const int wave = t >> 6, lane = t & 63;
  const int arow = lane & 15;
  const int kg = (lane >> 4) * 8;
  const int row0 = (lane >> 4) * 4;

  {  // off+att GEMM: [16x256] @ [256x384], wave covers 6 col-tiles
    floatx4 acc[6] = {};
    for (int kk = 0; kk < 8; ++kk) {
      const int k0 = kk * 32;
      short8 af = *(const short8*)&qs[arow][k0 + kg];
#pragma unroll
      for (int i = 0; i < 6; ++i) {
        const int col = wave * 96 + i * 16 + (lane & 15);
        const unsigned short* bp = (col < 256) ? (wt + col * 256)
                                               : (wt + 65536 + (col - 256) * 256);
        short8 bf = *(const short8*)(bp + k0 + kg);
        acc[i] = __builtin_amdgcn_mfma_f32_16x16x32_bf16(af, bf, acc[i], 0, 0, 0);
      }
    }
#pragma unroll
    for (int i = 0; i < 6; ++i) {
      const int col = wave * 96 + i * 16 + (lane & 15);
      const float bb = (col < 256) ? boff[col] : batt[col - 256];
#pragma unroll
      for (int j = 0; j < 4; ++j) oa[row0 + j][col] = acc[i][j] + bb;
    }
  }
  __syncthreads();

  if (t < 128) {  // softmax over 16 per (q, m): q = t>>3 in 0..15, m = t&7
    const int q = t >> 3, m = t & 7;
    float v[16]; float mx = -1e30f;
#pragma unroll
    for (int s = 0; s < 16; ++s) { v[s] = oa[q][256 + m * 16 + s]; mx = fmaxf(mx, v[s]); }
    float sum = 0.f;
#pragma unroll
    for (int s = 0; s < 16; ++s) { v[s] = __expf(v[s] - mx); sum += v[s]; }
    const float inv = 1.f / sum;
#pragma unroll
    for (int s = 0; s < 16; ++s) oa[q][256 + m * 16 + s] = v[s] * inv;
  }
  __syncthreads();

  // sampling: single barrier per q (double-buffered params).
  // Safety: setup(q+2) rewriting slot[q&1] is ordered after barrier(q+1),
  // which every thread reaches only after finishing gather(q).
  const int m_g = t >> 5;
  const int g = t & 31;
  const int p8 = g >> 3;             // corner 0..3
  const int d4 = (g & 7) * 4;        // 4 bf16 per lane
  const unsigned short* vbase = vproj + ((size_t)(n * M_ + m_g) * LEN_) * DH_ + d4;

  for (int q = 0; q < BQ; ++q) {
    const int slot = q & 1;
    if (t < 128) {
      const int l = (t >> 2) & 3;
      const int Wl = c_HW[l];
      const int st = c_start[l];
      const float rx = refp[(((size_t)(qg0 + q)) * L_ + l) * 2 + 0];
      const float ry = refp[(((size_t)(qg0 + q)) * L_ + l) * 2 + 1];
      const float gx = rx * (float)Wl + oa[q][2 * t]     - 0.5f;
      const float gy = ry * (float)Wl + oa[q][2 * t + 1] - 0.5f;
      const float fx0 = floorf(gx), fy0 = floorf(gy);
      const int x0 = (int)fx0, y0 = (int)fy0;
      const float wx1 = gx - fx0, wy1 = gy - fy0;
      const float wx0 = 1.f - wx1, wy0 = 1.f - wy1;
      const float a = oa[q][256 + t];
      const bool vx0 = (x0 >= 0) && (x0 < Wl);
      const bool vx1 = (x0 + 1 >= 0) && (x0 + 1 < Wl);
      const bool vy0 = (y0 >= 0) && (y0 < Wl);
      const bool vy1 = (y0 + 1 >= 0) && (y0 + 1 < Wl);
      idxs[slot][t][0] = (short)((vx0 && vy0) ? st + y0 * Wl + x0 : -1);
      idxs[slot][t][1] = (short)((vx1 && vy0) ? st + y0 * Wl + x0 + 1 : -1);
      idxs[slot][t][2] = (short)((vx0 && vy1) ? st + (y0 + 1) * Wl + x0 : -1);
      idxs[slot][t][3] = (short)((vx1 && vy1) ? st + (y0 + 1) * Wl + x0 + 1 : -1);
      wls[slot][t][0] = wy0 * wx0 * a;
      wls[slot][t][1] = wy0 * wx1 * a;
      wls[slot][t][2] = wy1 * wx0 * a;
      wls[slot][t][3] = wy1 * wx1 * a;
    }
    __syncthreads();

    float a0 = 0.f, a1 = 0.f, a2 = 0.f, a3 = 0.f;
    const int sidb = m_g * 16;
#pragma unroll
    for (int s = 0; s < 16; ++s) {
      const int ix = (int)idxs[slot][sidb + s][p8];
      const int ixc = (ix >= 0) ? ix : 0;
      const float wv = (ix >= 0) ? wls[slot][sidb + s][p8] : 0.f;
      const unsigned short* p = vbase + (size_t)ixc * DH_;
      const uint2 u = *(const uint2*)p;
      a0 += __builtin_bit_cast(float, u.x << 16) * wv;
      a1 += __builtin_bit_cast(float, u.x & 0xffff0000u) * wv;
      a2 += __builtin_bit_cast(float, u.y << 16) * wv;
      a3 += __builtin_bit_cast(float, u.y & 0xffff0000u) * wv;
    }
    a0 += __shfl_xor(a0, 8);  a1 += __shfl_xor(a1, 8);
    a2 += __shfl_xor(a2, 8);  a3 += __shfl_xor(a3, 8);
    a0 += __shfl_xor(a0, 16); a1 += __shfl_xor(a1, 16);
    a2 += __shfl_xor(a2, 16); a3 += __shfl_xor(a3, 16);
    if (g < 8) {
      unsigned int* mp = (unsigned int*)&qs[q][m_g * 32 + d4];
      mp[0] = (unsigned int)f2bf(a0) | ((unsigned int)f2bf(a1) << 16);
      mp[1] = (unsigned int)f2bf(a2) | ((unsigned int)f2bf(a3) << 16);
    }
  }
  __syncthreads();

  {  // out GEMM: mid [16x256] @ Wout [256x256], wave covers 4 col-tiles
    floatx4 acc[4] = {};
    for (int kk = 0; kk < 8; ++kk) {
      const int k0 = kk * 32;
      short8 af = *(const short8*)&qs[arow][k0 + kg];
#pragma unroll
      for (int i = 0; i < 4; ++i) {
        const int col = wave * 64 + i * 16 + (lane & 15);
        short8 bf = *(const short8*)(wt + 98304 + col * 256 + k0 + kg);
        acc[i] = __builtin_amdgcn_mfma_f32_16x16x32_bf16(af, bf, acc[i], 0, 0, 0);
      }
    }
#pragma unroll
    for (int i = 0; i < 4; ++i) {
      const int col = wave * 64 + i * 16 + (lane & 15);
      const float bb = bout[col];
#pragma unroll
      for (int j = 0; j < 4; ++j)
        out[(size_t)(qg0 + row0 + j) * D_ + col] = acc[i][j] + bb;
    }
  }
}

extern "C" void kernel_launch(void* const* d_in, const int* in_sizes, int n_in,
                              void* d_out, int out_size, void* d_ws, size_t ws_size,
                              hipStream_t stream) {
  const float* query = (const float*)d_in[0];
  const float* refp  = (const float*)d_in[1];
  const float* value = (const float*)d_in[2];
  const float* Wv    = (const float*)d_in[4];
  const float* bv    = (const float*)d_in[5];
  const float* Woff  = (const float*)d_in[6];
  const float* boff  = (const float*)d_in[7];
  const float* Watt  = (const float*)d_in[8];
  const float* batt  = (const float*)d_in[9];
  const float* Wout  = (const float*)d_in[10];
  const float* bout  = (const float*)d_in[11];
  float* out = (float*)d_out;

  unsigned short* vproj = (unsigned short*)d_ws;
  unsigned short* wt    = (unsigned short*)((char*)d_ws + WT_BYTE_OFF);
  const unsigned short* Wvt = wt + 163840;

  dim3 blk(256);
  hipLaunchKernelGGL(prep_kernel, dim3(896), blk, 0, stream, Woff, Watt, Wout, Wv, wt);
  hipLaunchKernelGGL(vproj_kernel, dim3((N_ * LEN_) / 64), blk, 0, stream, value, Wvt, bv, vproj);
  hipLaunchKernelGGL(msda_kernel, dim3((N_ * LQ_) / BQ), blk, 0, stream,
                     query, refp, wt, boff, batt, bout, vproj, out);
}